// Round 8
// baseline (4410.076 us; speedup 1.0000x reference)
//
#include <hip/hip_runtime.h>

// 8-layer transformer LM forward. V=128, E=512, L=8, H=8, B=4, T=1024.
// Round 8: PERSISTENT MEGA-KERNEL. Entire forward (cvt, embed, 8 layers, head,
// loss) in ONE 512-block launch with software grid barriers (tree: 16 padded
// sub-counters -> root -> release word; AGENT-scope acquire spins + s_sleep).
// 2 blocks/CU guaranteed resident (32 KB LDS, launch_bounds(256,2)) -> no
// deadlock. Kills ~400 us of inter-dispatch overhead (77 -> 2 dispatches).
// GEMM: BM=64/BN=64/BK=64, source-permuted global_load_lds swizzle (round 7,
// conflict-free, zero staging VGPRs).

#define V_  128
#define E_  512
#define L_  8
#define H_  8
#define B_  4
#define T_  1024
#define N_  (B_*T_)    // 4096 tokens
#define DH_ 64
#define E3_ 1536
#define NBLK 512
#define NBAR 96

typedef __attribute__((ext_vector_type(8))) short   bf16x8;   // MFMA A/B frag
typedef __attribute__((ext_vector_type(4))) float   floatx4;  // MFMA C/D frag

// swizzled LDS offset (ushort units): 64-wide rows, 8-elem blocks XORed by row&7
#define SW(row,k8) (((row) << 6) + ((((k8) ^ ((row) & 7))) << 3))

#define CVT_N0 6291456   // qkv  L*1536*512
#define CVT_N1 2097152   // per-square L*512*512
#define CVT_TOT (CVT_N0 + 4*CVT_N1 + V_*E_)

__device__ __forceinline__ unsigned short f2bf(float f) {
    union { float f; unsigned int i; } v; v.f = f;
    unsigned int x = v.i;
    return (unsigned short)((x + 0x7fffu + ((x >> 16) & 1u)) >> 16);  // RNE
}
__device__ __forceinline__ float bf2f(unsigned short u) {
    union { unsigned int i; float f; } v; v.i = ((unsigned int)u) << 16; return v.f;
}
__device__ __forceinline__ void gload_lds16(const void* g, void* l) {
    __builtin_amdgcn_global_load_lds(
        (const __attribute__((address_space(1))) unsigned int*)g,
        (__attribute__((address_space(3))) unsigned int*)l, 16, 0, 0);
}

// ---------------- barrier state zeroing (fresh counters every call) ----------------
__global__ void zero_kernel(unsigned* __restrict__ p, int n) {
    for (int i = blockIdx.x * blockDim.x + threadIdx.x; i < n; i += gridDim.x * blockDim.x)
        p[i] = 0u;
}

// ---------------- grid barrier: 16 padded subs -> root -> release word ----------------
// barmem layout per barrier b: subs at [b*272 + s*16] (s<16), root at [b*272+256].
// release word at [NBAR*272]. Monotonic: barrier b sets release = b+1.
__device__ __forceinline__ void gridbar(unsigned* __restrict__ barmem, int barid) {
    __syncthreads();
    if (threadIdx.x == 0) {
        __threadfence();                           // agent-scope release of stage writes
        unsigned* subs = barmem + barid * 272;
        unsigned* root = subs + 256;
        unsigned* rel  = barmem + NBAR * 272;
        if (atomicAdd(&subs[(blockIdx.x & 15) * 16], 1u) == (NBLK / 16) - 1u)
            if (atomicAdd(root, 1u) == 15u)
                __hip_atomic_store(rel, (unsigned)(barid + 1),
                                   __ATOMIC_RELEASE, __HIP_MEMORY_SCOPE_AGENT);
        while (__hip_atomic_load(rel, __ATOMIC_ACQUIRE, __HIP_MEMORY_SCOPE_AGENT)
               < (unsigned)(barid + 1))
            __builtin_amdgcn_s_sleep(8);
        __threadfence();                           // agent-scope acquire
    }
    __syncthreads();
}

// ---------------- GEMM tile: BM=64, BN=64, BK=64, swizzled gload staging ----------------
__device__ __forceinline__ void gemm_tile(
    const unsigned short* __restrict__ A, const unsigned short* __restrict__ W,
    const float* __restrict__ bias, float* Cf, unsigned short* Cb,
    int Nout, int K, int m0, int n0, int relu, unsigned short* lds, int tid)
{
    unsigned short* Asm = lds;           // 64x64 swizzled (8 KB)
    unsigned short* Bsm = lds + 4096;    // 64x64 swizzled (8 KB)
    int wv = tid >> 6, ln = tid & 63;
    int lquad = ln >> 4, lmod = ln & 15;

    floatx4 acc[4] = {};
    for (int k0 = 0; k0 < K; k0 += 64) {
        __syncthreads();                 // prev iter/job readers done
        #pragma unroll
        for (int c = 0; c < 2; ++c) {
            int cc = tid + 256 * c;
            int r = cc >> 3, k8s = (cc & 7) ^ (r & 7);   // source-permuted chunk
            gload_lds16(A + (size_t)(m0 + r) * K + k0 + 8 * k8s, Asm + 2048 * c + 512 * wv);
            gload_lds16(W + (size_t)(n0 + r) * K + k0 + 8 * k8s, Bsm + 2048 * c + 512 * wv);
        }
        __syncthreads();                 // drains vmcnt
        #pragma unroll
        for (int ks = 0; ks < 2; ++ks) {
            bf16x8 af = *(const bf16x8*)&Asm[SW(16 * wv + lmod, ks * 4 + lquad)];
            #pragma unroll
            for (int j = 0; j < 4; ++j) {
                bf16x8 bfr = *(const bf16x8*)&Bsm[SW(16 * j + lmod, ks * 4 + lquad)];
                acc[j] = __builtin_amdgcn_mfma_f32_16x16x32_bf16(af, bfr, acc[j], 0, 0, 0);
            }
        }
    }
    #pragma unroll
    for (int j = 0; j < 4; ++j) {
        int n = n0 + 16 * j + lmod;
        float bj = bias[n];
        #pragma unroll
        for (int v = 0; v < 4; ++v) {
            int m = m0 + 16 * wv + 4 * lquad + v;
            float val = acc[j][v] + bj;
            if (relu) val = fmaxf(val, 0.f);
            if (Cf) Cf[(size_t)m * Nout + n] = val;
            if (Cb) Cb[(size_t)m * Nout + n] = f2bf(val);
        }
    }
}

// ---------------- attention job (one 64-q tile of one head) ----------------
// Masked scores are ZERO (=> p = 1 exactly); suffix tiles via vtile sums.
__device__ __forceinline__ void attn_job(
    const unsigned short* __restrict__ qkv, const unsigned short* __restrict__ vt_g,
    const float* __restrict__ vtile, unsigned short* __restrict__ outb,
    int bh, int qt, unsigned short* lds, int tid)
{
    unsigned short* Qs = lds;            // [q][d] swizzled
    unsigned short* Ks = lds + 4096;     // [k][d] swizzled
    unsigned short* Vs = lds + 8192;     // [d][k] swizzled
    unsigned short* Ps = lds + 12288;    // [q][k] swizzled

    int wv = tid >> 6, ln = tid & 63;
    int lquad = ln >> 4, lmod = ln & 15;
    int b = bh >> 3, h = bh & 7;
    int q0 = qt * 64;
    const float scale = 0.125f;
    size_t base = (size_t)b * T_ * E3_ + h * 192;

    // stage Q (async; drained by the first in-loop barrier)
    #pragma unroll
    for (int c = 0; c < 2; ++c) {
        int cc = tid + 256 * c;
        int r = cc >> 3, k8s = (cc & 7) ^ (r & 7);
        gload_lds16(qkv + base + (size_t)(q0 + r) * E3_ + 8 * k8s, Qs + 2048 * c + 512 * wv);
    }

    float lrow[4] = {0.f, 0.f, 0.f, 0.f};
    floatx4 Oa[4] = {};

    for (int kt = 0; kt <= qt; ++kt) {
        int k0 = kt * 64;
        __syncthreads();
        #pragma unroll
        for (int c = 0; c < 2; ++c) {
            int cc = tid + 256 * c;
            int r = cc >> 3, k8s = (cc & 7) ^ (r & 7);
            gload_lds16(qkv + base + (size_t)(k0 + r) * E3_ + 64 + 8 * k8s,
                        Ks + 2048 * c + 512 * wv);
            gload_lds16(vt_g + ((size_t)(bh * 64 + r)) * T_ + k0 + 8 * k8s,
                        Vs + 2048 * c + 512 * wv);
        }
        __syncthreads();

        floatx4 sacc[4] = {};
        #pragma unroll
        for (int ks = 0; ks < 2; ++ks) {
            bf16x8 aq = *(const bf16x8*)&Qs[SW(16 * wv + lmod, ks * 4 + lquad)];
            #pragma unroll
            for (int j = 0; j < 4; ++j) {
                bf16x8 bk = *(const bf16x8*)&Ks[SW(16 * j + lmod, ks * 4 + lquad)];
                sacc[j] = __builtin_amdgcn_mfma_f32_16x16x32_bf16(aq, bk, sacc[j], 0, 0, 0);
            }
        }
        #pragma unroll
        for (int v = 0; v < 4; ++v) {
            int qg = q0 + 16 * wv + 4 * lquad + v;
            int row = 16 * wv + 4 * lquad + v;
            #pragma unroll
            for (int j = 0; j < 4; ++j) {
                int kg = k0 + 16 * j + lmod;
                float p = (kg <= qg) ? __expf(sacc[j][v] * scale) : 1.0f;
                lrow[v] += p;
                int col = 16 * j + lmod;
                Ps[SW(row, col >> 3) + (col & 7)] = f2bf(p);
            }
        }
        __syncthreads();
        #pragma unroll
        for (int ks = 0; ks < 2; ++ks) {
            bf16x8 ap = *(const bf16x8*)&Ps[SW(16 * wv + lmod, ks * 4 + lquad)];
            #pragma unroll
            for (int f = 0; f < 4; ++f) {
                bf16x8 bv = *(const bf16x8*)&Vs[SW(16 * f + lmod, ks * 4 + lquad)];
                Oa[f] = __builtin_amdgcn_mfma_f32_16x16x32_bf16(ap, bv, Oa[f], 0, 0, 0);
            }
        }
    }

    #pragma unroll
    for (int v = 0; v < 4; ++v)
        #pragma unroll
        for (int msk = 1; msk < 16; msk <<= 1) lrow[v] += __shfl_xor(lrow[v], msk);

    if (qt < 15) {
        float Km = (float)((15 - qt) * 64);
        #pragma unroll
        for (int v = 0; v < 4; ++v) lrow[v] += Km;
        #pragma unroll
        for (int f = 0; f < 4; ++f) {
            float sv = 0.f;
            for (int kt = qt + 1; kt < 16; ++kt)
                sv += vtile[((size_t)bh * 16 + kt) * 64 + 16 * f + lmod];
            #pragma unroll
            for (int v = 0; v < 4; ++v) Oa[f][v] += sv;
        }
    }

    #pragma unroll
    for (int f = 0; f < 4; ++f)
        #pragma unroll
        for (int v = 0; v < 4; ++v) {
            int q = q0 + 16 * wv + 4 * lquad + v;
            outb[(size_t)(b * T_ + q) * E_ + h * DH_ + 16 * f + lmod] = f2bf(Oa[f][v] / lrow[v]);
        }
}

// ---------------- residual add + LN (wave-per-row), 4 rows per job ----------------
__device__ __forceinline__ void ln_rows(
    const float* __restrict__ a, const float* __restrict__ r,
    const float* __restrict__ s, const float* __restrict__ bpar,
    float* __restrict__ outF, unsigned short* __restrict__ outB, int job, int tid)
{
    int wv = tid >> 6, ln = tid & 63;
    int n = job * 4 + wv;
    int e = ln * 8;
    size_t base = (size_t)n * E_ + e;
    float4 a0 = *(const float4*)&a[base],     a1 = *(const float4*)&a[base + 4];
    float4 r0 = *(const float4*)&r[base],     r1 = *(const float4*)&r[base + 4];
    float v[8] = {a0.x + r0.x, a0.y + r0.y, a0.z + r0.z, a0.w + r0.w,
                  a1.x + r1.x, a1.y + r1.y, a1.z + r1.z, a1.w + r1.w};

    float sm = 0.f;
    #pragma unroll
    for (int i = 0; i < 8; ++i) sm += v[i];
    #pragma unroll
    for (int msk = 1; msk < 64; msk <<= 1) sm += __shfl_xor(sm, msk);
    float mu = sm * (1.f / 512.f);

    float ss = 0.f;
    #pragma unroll
    for (int i = 0; i < 8; ++i) { v[i] -= mu; ss += v[i] * v[i]; }
    #pragma unroll
    for (int msk = 1; msk < 64; msk <<= 1) ss += __shfl_xor(ss, msk);
    float rstd = rsqrtf(ss * (1.f / 512.f) + 1e-5f);

    float4 sc0 = *(const float4*)&s[e],    sc1 = *(const float4*)&s[e + 4];
    float4 bp0 = *(const float4*)&bpar[e], bp1 = *(const float4*)&bpar[e + 4];
    float o[8];
    o[0] = v[0] * rstd * sc0.x + bp0.x; o[1] = v[1] * rstd * sc0.y + bp0.y;
    o[2] = v[2] * rstd * sc0.z + bp0.z; o[3] = v[3] * rstd * sc0.w + bp0.w;
    o[4] = v[4] * rstd * sc1.x + bp1.x; o[5] = v[5] * rstd * sc1.y + bp1.y;
    o[6] = v[6] * rstd * sc1.z + bp1.z; o[7] = v[7] * rstd * sc1.w + bp1.w;
    *(float4*)&outF[base]     = make_float4(o[0], o[1], o[2], o[3]);
    *(float4*)&outF[base + 4] = make_float4(o[4], o[5], o[6], o[7]);
    union { unsigned short u[8]; uint4 q; } pk;
    #pragma unroll
    for (int i = 0; i < 8; ++i) pk.u[i] = f2bf(o[i]);
    *(uint4*)&outB[base] = pk.q;
}

// ---------------- THE mega kernel ----------------
__global__ __launch_bounds__(256, 2) void mega_kernel(
    const int* __restrict__ toks, const int* __restrict__ tgts,
    const float* __restrict__ emb,
    const float* __restrict__ qkv_w,  const float* __restrict__ qkv_b,
    const float* __restrict__ aff1_w, const float* __restrict__ aff1_b,
    const float* __restrict__ aff2_w, const float* __restrict__ aff2_b,
    const float* __restrict__ ffn1_w, const float* __restrict__ ffn1_b,
    const float* __restrict__ ffn2_w, const float* __restrict__ ffn2_b,
    const float* __restrict__ ln1_s,  const float* __restrict__ ln1_b,
    const float* __restrict__ ln2_s,  const float* __restrict__ ln2_b,
    const float* __restrict__ head_w, const float* __restrict__ head_b,
    unsigned short* wb_all, float* x_f, unsigned short* x_b,
    unsigned short* qkv_bf, unsigned short* att_b, unsigned short* h_b,
    float* y_f, float* o1_f, unsigned short* o1_b,
    float* rowl, float* vtile, unsigned short* vt_g,
    float* out_logits, float* out_loss, unsigned* barmem)
{
    __shared__ unsigned short lds_u[16384];   // exactly 32 KB -> 2 blocks/CU
    int tid = threadIdx.x;
    int bid = blockIdx.x;
    int wv = tid >> 6, ln = tid & 63;
    int barid = 0;

    // ---- stage: weight cvt (fp32 -> bf16 arena) ----
    for (long i = (long)(bid * 256 + tid) * 4; i < CVT_TOT; i += (long)NBLK * 256 * 4) {
        const float* src; long off;
        if      (i < CVT_N0)            { src = qkv_w;  off = i; }
        else if (i < CVT_N0 + CVT_N1)   { src = aff1_w; off = i - CVT_N0; }
        else if (i < CVT_N0 + 2*CVT_N1) { src = aff2_w; off = i - CVT_N0 - CVT_N1; }
        else if (i < CVT_N0 + 3*CVT_N1) { src = ffn1_w; off = i - CVT_N0 - 2L*CVT_N1; }
        else if (i < CVT_N0 + 4*CVT_N1) { src = ffn2_w; off = i - CVT_N0 - 3L*CVT_N1; }
        else                            { src = head_w; off = i - CVT_N0 - 4L*CVT_N1; }
        float4 vv = *(const float4*)(src + off);
        ushort4 o; o.x = f2bf(vv.x); o.y = f2bf(vv.y); o.z = f2bf(vv.z); o.w = f2bf(vv.w);
        *(ushort4*)(wb_all + i) = o;
    }
    gridbar(barmem, barid++);

    // ---- stage: embedding ----
    for (int i = (bid * 256 + tid) * 4; i < N_ * E_; i += NBLK * 256 * 4) {
        int n = i >> 9, e = i & (E_ - 1);
        float4 vv = *(const float4*)&emb[toks[n] * E_ + e];
        *(float4*)&x_f[i] = vv;
        ushort4 o; o.x = f2bf(vv.x); o.y = f2bf(vv.y); o.z = f2bf(vv.z); o.w = f2bf(vv.w);
        *(ushort4*)&x_b[i] = o;
    }
    gridbar(barmem, barid++);

    unsigned short* wb_qkv  = wb_all;
    unsigned short* wb_aff1 = wb_qkv  + (size_t)CVT_N0;
    unsigned short* wb_aff2 = wb_aff1 + (size_t)CVT_N1;
    unsigned short* wb_ffn1 = wb_aff2 + (size_t)CVT_N1;
    unsigned short* wb_ffn2 = wb_ffn1 + (size_t)CVT_N1;
    unsigned short* wb_head = wb_ffn2 + (size_t)CVT_N1;

    for (int l = 0; l < L_; ++l) {
        // qkv GEMM: 1536 tiles
        for (int job = bid; job < 1536; job += NBLK) {
            int jm = job / 24, jn = job % 24;
            gemm_tile(x_b, wb_qkv + (size_t)l * E3_ * E_, qkv_b + (size_t)l * E3_,
                      nullptr, qkv_bf, E3_, E_, jm * 64, jn * 64, 0, lds_u, tid);
        }
        gridbar(barmem, barid++);

        // vprep: 512 jobs -> vt_g + vtile
        for (int job = bid; job < 512; job += NBLK) {
            int bh = job >> 4, kt = job & 15;
            int b = bh >> 3, h = bh & 7;
            int k0 = kt * 64;
            size_t vbase = (size_t)b * T_ * E3_ + h * 192 + 128;
            unsigned short vals[16];
            float s = 0.f;
            #pragma unroll
            for (int i = 0; i < 16; ++i) {
                vals[i] = qkv_bf[vbase + (size_t)(k0 + wv * 16 + i) * E3_ + ln];
                s += bf2f(vals[i]);
            }
            #pragma unroll
            for (int hf = 0; hf < 2; ++hf) {
                union { unsigned short u[8]; uint4 v; } pk;
                #pragma unroll
                for (int i = 0; i < 8; ++i) pk.u[i] = vals[hf * 8 + i];
                *(uint4*)&vt_g[((size_t)(bh * 64 + ln)) * T_ + k0 + wv * 16 + hf * 8] = pk.v;
            }
            float* part = (float*)lds_u;
            __syncthreads();
            part[wv * 64 + ln] = s;
            __syncthreads();
            if (tid < 64)
                vtile[((size_t)bh * 16 + kt) * 64 + tid] =
                    part[tid] + part[64 + tid] + part[128 + tid] + part[192 + tid];
        }
        gridbar(barmem, barid++);

        // attention: 512 jobs
        for (int job = bid; job < 512; job += NBLK)
            attn_job(qkv_bf, vt_g, vtile, att_b, job & 31, job >> 5, lds_u, tid);
        gridbar(barmem, barid++);

        // aff1 (relu): 512 tiles
        for (int job = bid; job < 512; job += NBLK)
            gemm_tile(att_b, wb_aff1 + (size_t)l * E_ * E_, aff1_b + (size_t)l * E_,
                      nullptr, h_b, E_, E_, (job >> 3) * 64, (job & 7) * 64, 1, lds_u, tid);
        gridbar(barmem, barid++);

        // aff2: 512 tiles -> y_f
        for (int job = bid; job < 512; job += NBLK)
            gemm_tile(h_b, wb_aff2 + (size_t)l * E_ * E_, aff2_b + (size_t)l * E_,
                      y_f, nullptr, E_, E_, (job >> 3) * 64, (job & 7) * 64, 0, lds_u, tid);
        gridbar(barmem, barid++);

        // ln1: 1024 jobs
        for (int job = bid; job < 1024; job += NBLK)
            ln_rows(y_f, x_f, ln1_s + (size_t)l * E_, ln1_b + (size_t)l * E_,
                    o1_f, o1_b, job, tid);
        gridbar(barmem, barid++);

        // ffn1 (relu): 512 tiles
        for (int job = bid; job < 512; job += NBLK)
            gemm_tile(o1_b, wb_ffn1 + (size_t)l * E_ * E_, ffn1_b + (size_t)l * E_,
                      nullptr, h_b, E_, E_, (job >> 3) * 64, (job & 7) * 64, 1, lds_u, tid);
        gridbar(barmem, barid++);

        // ffn2: 512 tiles -> y_f
        for (int job = bid; job < 512; job += NBLK)
            gemm_tile(h_b, wb_ffn2 + (size_t)l * E_ * E_, ffn2_b + (size_t)l * E_,
                      y_f, nullptr, E_, E_, (job >> 3) * 64, (job & 7) * 64, 0, lds_u, tid);
        gridbar(barmem, barid++);

        // ln2: 1024 jobs -> new x
        for (int job = bid; job < 1024; job += NBLK)
            ln_rows(o1_f, y_f, ln2_s + (size_t)l * E_, ln2_b + (size_t)l * E_,
                    x_f, x_b, job, tid);
        gridbar(barmem, barid++);
    }

    // head GEMM: 128 tiles -> fp32 logits straight into d_out
    for (int job = bid; job < 128; job += NBLK)
        gemm_tile(x_b, wb_head, head_b, out_logits, nullptr,
                  V_, E_, (job >> 1) * 64, (job & 1) * 64, 0, lds_u, tid);
    gridbar(barmem, barid++);

    // loss rows: wave-per-row (lane covers elems ln and ln+64), 4 rows/job
    for (int job = bid; job < 1024; job += NBLK) {
        int row = job * 4 + wv;
        float x0 = out_logits[(size_t)row * V_ + ln];
        float x1 = out_logits[(size_t)row * V_ + 64 + ln];
        int t = tgts[row];
        float xt_c = (t < 64) ? x0 : x1;
        float xt = __shfl(xt_c, t & 63, 64);
        float m = fmaxf(x0, x1);
        #pragma unroll
        for (int msk = 1; msk < 64; msk <<= 1) m = fmaxf(m, __shfl_xor(m, msk));
        float se = __expf(x0 - m) + __expf(x1 - m);
        float sx = x0 + x1;
        #pragma unroll
        for (int msk = 1; msk < 64; msk <<= 1) {
            se += __shfl_xor(se, msk);
            sx += __shfl_xor(sx, msk);
        }
        if (ln == 0) {
            float lse = m + __logf(se);
            rowl[row] = 0.9f * (lse - xt) + 0.1f * (lse - sx * (1.f / 128.f));
        }
    }
    gridbar(barmem, barid++);

    // final loss reduce (block 0 only)
    if (bid == 0) {
        float s = 0.f;
        for (int i = tid; i < N_; i += 256) s += rowl[i];
        #pragma unroll
        for (int msk = 1; msk < 64; msk <<= 1) s += __shfl_xor(s, msk);
        float* lf = (float*)lds_u;
        __syncthreads();
        if (ln == 0) lf[wv] = s;
        __syncthreads();
        if (tid == 0) out_loss[0] = (lf[0] + lf[1] + lf[2] + lf[3]) * (1.f / (float)N_);
    }
}

extern "C" void kernel_launch(void* const* d_in, const int* in_sizes, int n_in,
                              void* d_out, int out_size, void* d_ws, size_t ws_size,
                              hipStream_t stream)
{
    (void)in_sizes; (void)n_in; (void)out_size; (void)ws_size;
    const int* toks     = (const int*)d_in[0];
    const int* tgts     = (const int*)d_in[1];
    const float* emb    = (const float*)d_in[2];
    const float* qkv_w  = (const float*)d_in[3];
    const float* qkv_b  = (const float*)d_in[4];
    const float* aff1_w = (const float*)d_in[5];
    const float* aff1_b = (const float*)d_in[6];
    const float* aff2_w = (const float*)d_in[7];
    const float* aff2_b = (const float*)d_in[8];
    const float* ffn1_w = (const float*)d_in[9];
    const float* ffn1_b = (const float*)d_in[10];
    const float* ffn2_w = (const float*)d_in[11];
    const float* ffn2_b = (const float*)d_in[12];
    const float* ln1_s  = (const float*)d_in[13];
    const float* ln1_b  = (const float*)d_in[14];
    const float* ln2_s  = (const float*)d_in[15];
    const float* ln2_b  = (const float*)d_in[16];
    const float* head_w = (const float*)d_in[17];
    const float* head_b = (const float*)d_in[18];

    char* p = (char*)d_ws;
    auto carve = [&](size_t bytes) { char* r = p; p += (bytes + 255) & ~(size_t)255; return (void*)r; };
    unsigned short* wb_all  = (unsigned short*)carve((size_t)CVT_TOT * 2);
    float*          x_f     = (float*)carve((size_t)N_ * E_ * 4);
    unsigned short* x_b     = (unsigned short*)carve((size_t)N_ * E_ * 2);
    unsigned short* qkv_bf  = (unsigned short*)carve((size_t)N_ * E3_ * 2);
    unsigned short* att_b   = (unsigned short*)carve((size_t)N_ * E_ * 2);
    unsigned short* h_b     = (unsigned short*)carve((size_t)N_ * E_ * 2);
    float*          y_f     = (float*)carve((size_t)N_ * E_ * 4);
    float*          o1_f    = (float*)carve((size_t)N_ * E_ * 4);
    unsigned short* o1_b    = (unsigned short*)carve((size_t)N_ * E_ * 2);
    float*          rowl    = (float*)carve((size_t)N_ * 4);
    float*          vtile   = (float*)carve((size_t)32 * 16 * 64 * 4);
    unsigned short* vt_g    = (unsigned short*)carve((size_t)32 * 64 * T_ * 2);
    unsigned*       barmem  = (unsigned*)carve((size_t)(NBAR * 272 + 16) * 4);

    float* out_logits = (float*)d_out;
    float* out_loss   = out_logits + (size_t)N_ * V_;

    zero_kernel<<<dim3(64), 256, 0, stream>>>(barmem, NBAR * 272 + 16);
    mega_kernel<<<dim3(NBLK), 256, 0, stream>>>(
        toks, tgts, emb, qkv_w, qkv_b, aff1_w, aff1_b, aff2_w, aff2_b,
        ffn1_w, ffn1_b, ffn2_w, ffn2_b, ln1_s, ln1_b, ln2_s, ln2_b, head_w, head_b,
        wb_all, x_f, x_b, qkv_bf, att_b, h_b, y_f, o1_f, o1_b,
        rowl, vtile, vt_g, out_logits, out_loss, barmem);
}

// Round 9
// 976.181 us; speedup vs baseline: 4.5177x; 4.5177x over previous
//
#include <hip/hip_runtime.h>

// 8-layer transformer LM forward. V=128, E=512, L=8, H=8, B=4, T=1024.
// Round 9: revert to round-7 multi-kernel structure (mega-kernel was HBM-bound
// by per-barrier L2 invalidation on 8 XCDs). New: full-row fused GEMM+LN
// (BM=16/BN=512/BK=32, grid 256) for aff2+ln1 and ffn2+ln2; head GEMM writes
// d_out directly; loss = memset + single atomicAdd kernel. 77 -> 61 dispatches.

#define V_  128
#define E_  512
#define L_  8
#define H_  8
#define B_  4
#define T_  1024
#define N_  (B_*T_)    // 4096 tokens
#define DH_ 64
#define E3_ 1536

typedef __attribute__((ext_vector_type(8))) short   bf16x8;   // MFMA A/B frag
typedef __attribute__((ext_vector_type(4))) float   floatx4;  // MFMA C/D frag

// swizzled LDS offset, 64-ushort rows (GEMM/attn tiles): 8-blk XOR by row&7
#define SW(row,k8) (((row) << 6) + ((((k8) ^ ((row) & 7))) << 3))
// swizzled LDS offset, 32-ushort rows (gemm_ln tiles): XOR by (row>>1)&3
#define SW32(row,k8) (((row) << 5) + ((((k8) ^ (((row) >> 1) & 3))) << 3))

__device__ __forceinline__ unsigned short f2bf(float f) {
    union { float f; unsigned int i; } v; v.f = f;
    unsigned int x = v.i;
    return (unsigned short)((x + 0x7fffu + ((x >> 16) & 1u)) >> 16);  // RNE
}
__device__ __forceinline__ float bf2f(unsigned short u) {
    union { unsigned int i; float f; } v; v.i = ((unsigned int)u) << 16; return v.f;
}
__device__ __forceinline__ void gload_lds16(const void* g, void* l) {
    __builtin_amdgcn_global_load_lds(
        (const __attribute__((address_space(1))) unsigned int*)g,
        (__attribute__((address_space(3))) unsigned int*)l, 16, 0, 0);
}

// ---------------- single-dispatch fp32 -> bf16 weight convert ----------------
#define CVT_N0 6291456   // qkv  L*1536*512
#define CVT_N1 2097152   // per-square L*512*512
#define CVT_TOT (CVT_N0 + 4*CVT_N1 + V_*E_)
__global__ void cvt_all_kernel(const float* __restrict__ s0, const float* __restrict__ s1,
                               const float* __restrict__ s2, const float* __restrict__ s3,
                               const float* __restrict__ s4, const float* __restrict__ s5,
                               unsigned short* __restrict__ dst) {
    long i = (long)(blockIdx.x * blockDim.x + threadIdx.x) * 4;
    if (i >= CVT_TOT) return;
    const float* src; long off;
    if      (i < CVT_N0)               { src = s0; off = i; }
    else if (i < CVT_N0 + CVT_N1)      { src = s1; off = i - CVT_N0; }
    else if (i < CVT_N0 + 2*CVT_N1)    { src = s2; off = i - CVT_N0 - CVT_N1; }
    else if (i < CVT_N0 + 3*CVT_N1)    { src = s3; off = i - CVT_N0 - 2L*CVT_N1; }
    else if (i < CVT_N0 + 4*CVT_N1)    { src = s4; off = i - CVT_N0 - 3L*CVT_N1; }
    else                               { src = s5; off = i - CVT_N0 - 4L*CVT_N1; }
    float4 v = *(const float4*)(src + off);
    ushort4 o; o.x = f2bf(v.x); o.y = f2bf(v.y); o.z = f2bf(v.z); o.w = f2bf(v.w);
    *(ushort4*)(dst + i) = o;
}

// ---------------- embedding: write fp32 + bf16 ----------------
__global__ void embed_kernel(const int* __restrict__ tok, const float* __restrict__ emb,
                             float* __restrict__ xf, unsigned short* __restrict__ xb) {
    int idx = blockIdx.x * blockDim.x + threadIdx.x;
    if (idx >= N_ * E_) return;
    int n = idx >> 9;
    int e = idx & (E_ - 1);
    float v = emb[tok[n] * E_ + e];
    xf[idx] = v; xb[idx] = f2bf(v);
}

// ---------------- MFMA GEMM: BM=128, BN=64, BK=64 (round-7 verified) ----------------
template<int RELU, int WF, int WB>
__global__ __launch_bounds__(256) void gemm_mfma(
    const unsigned short* __restrict__ A, const unsigned short* __restrict__ W,
    const float* __restrict__ bias, float* __restrict__ Cf, unsigned short* __restrict__ Cb,
    int M, int Nout, int K)
{
    __shared__ unsigned short Asm[128 * 64];   // 16 KB, swizzled
    __shared__ unsigned short Bsm[64 * 64];    //  8 KB, swizzled
    int tid = threadIdx.x;
    int wv = tid >> 6, ln = tid & 63;
    int lquad = ln >> 4, lmod = ln & 15;
    int m0 = blockIdx.y * 128, n0 = blockIdx.x * 64;

    floatx4 acc[2][4] = {};

    for (int k0 = 0; k0 < K; k0 += 64) {
        __syncthreads();
        #pragma unroll
        for (int c = 0; c < 4; ++c) {
            int cc = tid + 256 * c;
            int r = cc >> 3, k8s = (cc & 7) ^ (r & 7);   // source-permuted chunk
            gload_lds16(A + (size_t)(m0 + r) * K + k0 + 8 * k8s, Asm + 2048 * c + 512 * wv);
        }
        #pragma unroll
        for (int c = 0; c < 2; ++c) {
            int cc = tid + 256 * c;
            int r = cc >> 3, k8s = (cc & 7) ^ (r & 7);
            gload_lds16(W + (size_t)(n0 + r) * K + k0 + 8 * k8s, Bsm + 2048 * c + 512 * wv);
        }
        __syncthreads();
        #pragma unroll
        for (int ks = 0; ks < 2; ++ks) {
            bf16x8 af[2], bfr[4];
            #pragma unroll
            for (int i = 0; i < 2; ++i)
                af[i] = *(const bf16x8*)&Asm[SW(32 * wv + 16 * i + lmod, ks * 4 + lquad)];
            #pragma unroll
            for (int j = 0; j < 4; ++j)
                bfr[j] = *(const bf16x8*)&Bsm[SW(16 * j + lmod, ks * 4 + lquad)];
            #pragma unroll
            for (int i = 0; i < 2; ++i)
                #pragma unroll
                for (int j = 0; j < 4; ++j)
                    acc[i][j] = __builtin_amdgcn_mfma_f32_16x16x32_bf16(af[i], bfr[j], acc[i][j], 0, 0, 0);
        }
    }
    #pragma unroll
    for (int i = 0; i < 2; ++i)
        #pragma unroll
        for (int j = 0; j < 4; ++j) {
            int n = n0 + 16 * j + lmod;
            float bj = bias[n];
            #pragma unroll
            for (int v = 0; v < 4; ++v) {
                int m = m0 + 32 * wv + 16 * i + 4 * lquad + v;
                float val = acc[i][j][v] + bj;
                if (RELU) val = fmaxf(val, 0.f);
                if (WF) Cf[(size_t)m * Nout + n] = val;
                if (WB) Cb[(size_t)m * Nout + n] = f2bf(val);
            }
        }
}

// ---------------- fused full-row GEMM + residual + LayerNorm ----------------
// C[m,:] = LN(A[m,:]·W^T + bias + res[m,:]) * s + b.  BM=16, BN=512, BK=32.
// Grid 256 (m-tiles). Block owns 16 COMPLETE rows -> LN in epilogue.
// Wave w covers cols 128w..128w+127 (8 col-frags); rows shared by all waves.
__global__ __launch_bounds__(256) void gemm_ln(
    const unsigned short* __restrict__ A, const unsigned short* __restrict__ W,
    const float* __restrict__ bias, const float* __restrict__ res,
    const float* __restrict__ lnS, const float* __restrict__ lnB,
    float* __restrict__ outF, unsigned short* __restrict__ outB)
{
    __shared__ unsigned short As[16 * 32];    //  1 KB, swizzled(32)
    __shared__ unsigned short Bs[512 * 32];   // 32 KB, swizzled(32)
    __shared__ float red[2][64];              // stats scratch [pass][wv*16+row]
    int tid = threadIdx.x;
    int wv = tid >> 6, ln = tid & 63;
    int lquad = ln >> 4, lmod = ln & 15;
    int m0 = blockIdx.x * 16;

    floatx4 acc[8] = {};

    for (int k0 = 0; k0 < E_; k0 += 32) {
        __syncthreads();
        // B tile 512x32 (2048 chunks): 8 gloads/thread, source-permuted
        #pragma unroll
        for (int c = 0; c < 8; ++c) {
            int cc = tid + 256 * c;
            int r = cc >> 2, k8s = (cc & 3) ^ ((r >> 1) & 3);
            gload_lds16(W + (size_t)r * E_ + k0 + 8 * k8s, Bs + 2048 * c + 512 * wv);
        }
        // A tile 16x32 (64 chunks): wave 0 only
        if (wv == 0) {
            int r = ln >> 2, k8s = (ln & 3) ^ ((r >> 1) & 3);
            gload_lds16(A + (size_t)(m0 + r) * E_ + k0 + 8 * k8s, As);
        }
        __syncthreads();
        bf16x8 af = *(const bf16x8*)&As[SW32(lmod, lquad)];
        #pragma unroll
        for (int j = 0; j < 8; ++j) {
            bf16x8 bfr = *(const bf16x8*)&Bs[SW32(128 * wv + 16 * j + lmod, lquad)];
            acc[j] = __builtin_amdgcn_mfma_f32_16x16x32_bf16(af, bfr, acc[j], 0, 0, 0);
        }
    }

    // epilogue: val = acc + bias + res (rows m0+4*lquad+v, cols 128wv+16j+lmod)
    float val[8][4];
    #pragma unroll
    for (int j = 0; j < 8; ++j) {
        int col = 128 * wv + 16 * j + lmod;
        float bj = bias[col];
        #pragma unroll
        for (int v = 0; v < 4; ++v) {
            int m = m0 + 4 * lquad + v;
            val[j][v] = acc[j][v] + bj + res[(size_t)m * E_ + col];
        }
    }
    // pass 1: row sums -> mu (two-pass LN, matches reference numerics)
    float ps[4];
    #pragma unroll
    for (int v = 0; v < 4; ++v) {
        float s = 0.f;
        #pragma unroll
        for (int j = 0; j < 8; ++j) s += val[j][v];
        #pragma unroll
        for (int msk = 1; msk < 16; msk <<= 1) s += __shfl_xor(s, msk);
        ps[v] = s;
    }
    __syncthreads();   // all waves done reading Bs/As (MFMA consumed)
    if (lmod == 0)
        #pragma unroll
        for (int v = 0; v < 4; ++v) red[0][wv * 16 + 4 * lquad + v] = ps[v];
    __syncthreads();
    float mu[4];
    #pragma unroll
    for (int v = 0; v < 4; ++v) {
        int r = 4 * lquad + v;
        mu[v] = (red[0][r] + red[0][16 + r] + red[0][32 + r] + red[0][48 + r]) * (1.f / 512.f);
    }
    // pass 2: row sumsq of (val - mu) -> rstd
    #pragma unroll
    for (int v = 0; v < 4; ++v) {
        float s = 0.f;
        #pragma unroll
        for (int j = 0; j < 8; ++j) { float d = val[j][v] - mu[v]; s += d * d; }
        #pragma unroll
        for (int msk = 1; msk < 16; msk <<= 1) s += __shfl_xor(s, msk);
        ps[v] = s;
    }
    if (lmod == 0)
        #pragma unroll
        for (int v = 0; v < 4; ++v) red[1][wv * 16 + 4 * lquad + v] = ps[v];
    __syncthreads();
    float rstd[4];
    #pragma unroll
    for (int v = 0; v < 4; ++v) {
        int r = 4 * lquad + v;
        float var = (red[1][r] + red[1][16 + r] + red[1][32 + r] + red[1][48 + r]) * (1.f / 512.f);
        rstd[v] = rsqrtf(var + 1e-5f);
    }
    // write
    #pragma unroll
    for (int j = 0; j < 8; ++j) {
        int col = 128 * wv + 16 * j + lmod;
        float sc = lnS[col], bb = lnB[col];
        #pragma unroll
        for (int v = 0; v < 4; ++v) {
            int m = m0 + 4 * lquad + v;
            float o = (val[j][v] - mu[v]) * rstd[v] * sc + bb;
            outF[(size_t)m * E_ + col] = o;
            outB[(size_t)m * E_ + col] = f2bf(o);
        }
    }
}

// ---------------- vprep: V transpose -> vt_g[bh][d][k] + tile sums ----------------
__global__ __launch_bounds__(256) void vprep_kernel(const unsigned short* __restrict__ qkv,
                                                    unsigned short* __restrict__ vt_g,
                                                    float* __restrict__ vtile) {
    int bh = blockIdx.x, kt = blockIdx.y;
    int b = bh >> 3, h = bh & 7;
    int tid = threadIdx.x, wv = tid >> 6, ln = tid & 63;
    int k0 = kt * 64;
    size_t base = (size_t)b * T_ * E3_ + h * 192 + 128;

    unsigned short vals[16];
    float s = 0.f;
    #pragma unroll
    for (int i = 0; i < 16; ++i) {
        vals[i] = qkv[base + (size_t)(k0 + wv * 16 + i) * E3_ + ln];
        s += bf2f(vals[i]);
    }
    #pragma unroll
    for (int hf = 0; hf < 2; ++hf) {
        union { unsigned short u[8]; uint4 v; } pk;
        #pragma unroll
        for (int i = 0; i < 8; ++i) pk.u[i] = vals[hf * 8 + i];
        *(uint4*)&vt_g[((size_t)(bh * 64 + ln)) * T_ + k0 + wv * 16 + hf * 8] = pk.v;
    }
    __shared__ float part[4][64];
    part[wv][ln] = s;
    __syncthreads();
    if (tid < 64)
        vtile[((size_t)bh * 16 + kt) * 64 + tid] =
            part[0][tid] + part[1][tid] + part[2][tid] + part[3][tid];
}

// ---------------- MFMA flash attention (round-7 verified) ----------------
__global__ __launch_bounds__(256) void attn_mfma(const unsigned short* __restrict__ qkv,
                                                 const unsigned short* __restrict__ vt_g,
                                                 const float* __restrict__ vtile,
                                                 unsigned short* __restrict__ outb)
{
    __shared__ unsigned short Qs[64 * 64];
    __shared__ unsigned short Ks[64 * 64];
    __shared__ unsigned short Vs[64 * 64];
    __shared__ unsigned short Ps[64 * 64];

    int tid = threadIdx.x;
    int wv = tid >> 6, ln = tid & 63;
    int lquad = ln >> 4, lmod = ln & 15;
    int bh = blockIdx.x, qt = blockIdx.y;
    int b = bh >> 3, h = bh & 7;
    int q0 = qt * 64;
    const float scale = 0.125f;
    size_t base = (size_t)b * T_ * E3_ + h * 192;

    #pragma unroll
    for (int c = 0; c < 2; ++c) {
        int cc = tid + 256 * c;
        int r = cc >> 3, k8s = (cc & 7) ^ (r & 7);
        gload_lds16(qkv + base + (size_t)(q0 + r) * E3_ + 8 * k8s, Qs + 2048 * c + 512 * wv);
    }

    float lrow[4] = {0.f, 0.f, 0.f, 0.f};
    floatx4 Oa[4] = {};

    for (int kt = 0; kt <= qt; ++kt) {
        int k0 = kt * 64;
        __syncthreads();
        #pragma unroll
        for (int c = 0; c < 2; ++c) {
            int cc = tid + 256 * c;
            int r = cc >> 3, k8s = (cc & 7) ^ (r & 7);
            gload_lds16(qkv + base + (size_t)(k0 + r) * E3_ + 64 + 8 * k8s,
                        Ks + 2048 * c + 512 * wv);
            gload_lds16(vt_g + ((size_t)(bh * 64 + r)) * T_ + k0 + 8 * k8s,
                        Vs + 2048 * c + 512 * wv);
        }
        __syncthreads();

        floatx4 sacc[4] = {};
        #pragma unroll
        for (int ks = 0; ks < 2; ++ks) {
            bf16x8 aq = *(const bf16x8*)&Qs[SW(16 * wv + lmod, ks * 4 + lquad)];
            #pragma unroll
            for (int j = 0; j < 4; ++j) {
                bf16x8 bk = *(const bf16x8*)&Ks[SW(16 * j + lmod, ks * 4 + lquad)];
                sacc[j] = __builtin_amdgcn_mfma_f32_16x16x32_bf16(aq, bk, sacc[j], 0, 0, 0);
            }
        }
        #pragma unroll
        for (int v = 0; v < 4; ++v) {
            int qg = q0 + 16 * wv + 4 * lquad + v;
            int row = 16 * wv + 4 * lquad + v;
            #pragma unroll
            for (int j = 0; j < 4; ++j) {
                int kg = k0 + 16 * j + lmod;
                float p = (kg <= qg) ? __expf(sacc[j][v] * scale) : 1.0f;
                lrow[v] += p;
                int col = 16 * j + lmod;
                Ps[SW(row, col >> 3) + (col & 7)] = f2bf(p);
            }
        }
        __syncthreads();
        #pragma unroll
        for (int ks = 0; ks < 2; ++ks) {
            bf16x8 ap = *(const bf16x8*)&Ps[SW(16 * wv + lmod, ks * 4 + lquad)];
            #pragma unroll
            for (int f = 0; f < 4; ++f) {
                bf16x8 bv = *(const bf16x8*)&Vs[SW(16 * f + lmod, ks * 4 + lquad)];
                Oa[f] = __builtin_amdgcn_mfma_f32_16x16x32_bf16(ap, bv, Oa[f], 0, 0, 0);
            }
        }
    }

    #pragma unroll
    for (int v = 0; v < 4; ++v)
        #pragma unroll
        for (int msk = 1; msk < 16; msk <<= 1) lrow[v] += __shfl_xor(lrow[v], msk);

    if (qt < 15) {
        float Km = (float)((15 - qt) * 64);
        #pragma unroll
        for (int v = 0; v < 4; ++v) lrow[v] += Km;
        #pragma unroll
        for (int f = 0; f < 4; ++f) {
            float sv = 0.f;
            for (int kt = qt + 1; kt < 16; ++kt)
                sv += vtile[((size_t)bh * 16 + kt) * 64 + 16 * f + lmod];
            #pragma unroll
            for (int v = 0; v < 4; ++v) Oa[f][v] += sv;
        }
    }

    #pragma unroll
    for (int f = 0; f < 4; ++f)
        #pragma unroll
        for (int v = 0; v < 4; ++v) {
            int q = q0 + 16 * wv + 4 * lquad + v;
            outb[(size_t)(b * T_ + q) * E_ + h * DH_ + 16 * f + lmod] = f2bf(Oa[f][v] / lrow[v]);
        }
}

// ---------------- loss: reads logits from d_out, atomicAdd into out_loss ----------------
// Grid 512 x 256 thr; wave handles 2 rows (lane covers logit ln and 64+ln).
__global__ __launch_bounds__(256) void loss_kernel(
    const float* __restrict__ logits, const int* __restrict__ tgt,
    float* __restrict__ out_loss)
{
    int tid = threadIdx.x, wv = tid >> 6, ln = tid & 63;
    float part = 0.f;
    #pragma unroll
    for (int rr = 0; rr < 2; ++rr) {
        int row = blockIdx.x * 8 + wv * 2 + rr;
        float x0 = logits[(size_t)row * V_ + ln];
        float x1 = logits[(size_t)row * V_ + 64 + ln];
        int t = tgt[row];
        float xt_c = (t < 64) ? x0 : x1;
        float xt = __shfl(xt_c, t & 63, 64);
        float m = fmaxf(x0, x1);
        #pragma unroll
        for (int msk = 1; msk < 64; msk <<= 1) m = fmaxf(m, __shfl_xor(m, msk));
        float se = __expf(x0 - m) + __expf(x1 - m);
        float sx = x0 + x1;
        #pragma unroll
        for (int msk = 1; msk < 64; msk <<= 1) {
            se += __shfl_xor(se, msk);
            sx += __shfl_xor(sx, msk);
        }
        float lse = m + __logf(se);
        part += 0.9f * (lse - xt) + 0.1f * (lse - sx * (1.f / 128.f));
    }
    __shared__ float red[4];
    if (ln == 0) red[wv] = part;
    __syncthreads();
    if (tid == 0)
        atomicAdd(out_loss, (red[0] + red[1] + red[2] + red[3]) * (1.f / (float)N_));
}

extern "C" void kernel_launch(void* const* d_in, const int* in_sizes, int n_in,
                              void* d_out, int out_size, void* d_ws, size_t ws_size,
                              hipStream_t stream)
{
    (void)in_sizes; (void)n_in; (void)out_size; (void)ws_size;
    const int* toks     = (const int*)d_in[0];
    const int* tgts     = (const int*)d_in[1];
    const float* emb    = (const float*)d_in[2];
    const float* qkv_w  = (const float*)d_in[3];
    const float* qkv_b  = (const float*)d_in[4];
    const float* aff1_w = (const float*)d_in[5];
    const float* aff1_b = (const float*)d_in[6];
    const float* aff2_w = (const float*)d_in[7];
    const float* aff2_b = (const float*)d_in[8];
    const float* ffn1_w = (const float*)d_in[9];
    const float* ffn1_b = (const float*)d_in[10];
    const float* ffn2_w = (const float*)d_in[11];
    const float* ffn2_b = (const float*)d_in[12];
    const float* ln1_s  = (const float*)d_in[13];
    const float* ln1_b  = (const float*)d_in[14];
    const float* ln2_s  = (const float*)d_in[15];
    const float* ln2_b  = (const float*)d_in[16];
    const float* head_w = (const float*)d_in[17];
    const float* head_b = (const float*)d_in[18];

    char* p = (char*)d_ws;
    auto carve = [&](size_t bytes) { char* r = p; p += (bytes + 255) & ~(size_t)255; return (void*)r; };
    unsigned short* wb_all  = (unsigned short*)carve((size_t)CVT_TOT * 2);
    unsigned short* wb_qkv  = wb_all;
    unsigned short* wb_aff1 = wb_qkv  + (size_t)CVT_N0;
    unsigned short* wb_aff2 = wb_aff1 + (size_t)CVT_N1;
    unsigned short* wb_ffn1 = wb_aff2 + (size_t)CVT_N1;
    unsigned short* wb_ffn2 = wb_ffn1 + (size_t)CVT_N1;
    unsigned short* wb_head = wb_ffn2 + (size_t)CVT_N1;
    float*          x_f     = (float*)carve((size_t)N_ * E_ * 4);
    unsigned short* x_b     = (unsigned short*)carve((size_t)N_ * E_ * 2);
    unsigned short* qkv_bf  = (unsigned short*)carve((size_t)N_ * E3_ * 2);
    unsigned short* att_b   = (unsigned short*)carve((size_t)N_ * E_ * 2);
    unsigned short* h_b     = (unsigned short*)carve((size_t)N_ * E_ * 2);
    float*          o1_f    = (float*)carve((size_t)N_ * E_ * 4);
    unsigned short* o1_b    = (unsigned short*)carve((size_t)N_ * E_ * 2);
    float*          vtile   = (float*)carve((size_t)32 * 16 * 64 * 4);
    unsigned short* vt_g    = (unsigned short*)carve((size_t)32 * 64 * T_ * 2);

    float* out_logits = (float*)d_out;
    float* out_loss   = out_logits + (size_t)N_ * V_;

    cvt_all_kernel<<<dim3(CVT_TOT / 1024), 256, 0, stream>>>(
        qkv_w, aff1_w, aff2_w, ffn1_w, ffn2_w, head_w, wb_all);

    embed_kernel<<<dim3((N_ * E_) / 256), 256, 0, stream>>>(toks, emb, x_f, x_b);

    for (int l = 0; l < L_; ++l) {
        gemm_mfma<0,0,1><<<dim3(E3_/64, N_/128), 256, 0, stream>>>(
            x_b, wb_qkv + (size_t)l * E3_ * E_, qkv_b + (size_t)l * E3_,
            nullptr, qkv_bf, N_, E3_, E_);
        vprep_kernel<<<dim3(32, 16), 256, 0, stream>>>(qkv_bf, vt_g, vtile);
        attn_mfma<<<dim3(32, 16), 256, 0, stream>>>(qkv_bf, vt_g, vtile, att_b);
        gemm_mfma<1,0,1><<<dim3(E_/64, N_/128), 256, 0, stream>>>(
            att_b, wb_aff1 + (size_t)l * E_ * E_, aff1_b + (size_t)l * E_,
            nullptr, h_b, N_, E_, E_);
        gemm_ln<<<dim3(N_/16), 256, 0, stream>>>(
            h_b, wb_aff2 + (size_t)l * E_ * E_, aff2_b + (size_t)l * E_,
            x_f, ln1_s + (size_t)l * E_, ln1_b + (size_t)l * E_, o1_f, o1_b);
        gemm_mfma<1,0,1><<<dim3(E_/64, N_/128), 256, 0, stream>>>(
            o1_b, wb_ffn1 + (size_t)l * E_ * E_, ffn1_b + (size_t)l * E_,
            nullptr, h_b, N_, E_, E_);
        gemm_ln<<<dim3(N_/16), 256, 0, stream>>>(
            h_b, wb_ffn2 + (size_t)l * E_ * E_, ffn2_b + (size_t)l * E_,
            o1_f, ln2_s + (size_t)l * E_, ln2_b + (size_t)l * E_, x_f, x_b);
    }

    gemm_mfma<0,1,0><<<dim3(V_/64, N_/128), 256, 0, stream>>>(
        x_b, wb_head, head_b, out_logits, nullptr, N_, V_, E_);
    hipMemsetAsync(out_loss, 0, 4, stream);
    loss_kernel<<<dim3(N_/8), 256, 0, stream>>>(out_logits, tgts, out_loss);
}